// Round 1
// baseline (702.302 us; speedup 1.0000x reference)
//
#include <hip/hip_runtime.h>

// HNM discriminative loss, MI355X.
// predict (4,32,512,1024) f32, target (4,512,1024) i32 -> scalar f32.
// Two HBM passes (sums/counts, then residuals) + tiny finalize.

#define K_CLS 19
#define C_CH 32
#define HW_SHIFT 19            // H*W = 512*1024 = 2^19
#define HW_SIZE (1 << HW_SHIFT)
#define EPSF 1e-12f
#define THEA_F 0.5f
#define TWO_DELTA 3.0f
#define MIN_PIX 20.0f

// ws float layout
#define OFF_SUMS 0             // 608 floats, layout [ch][cls] = ch*19 + s
#define OFF_CNT  608           // 19
#define OFF_SQ   627           // 19
#define OFF_POS  646           // 19
#define WS_FLOATS 665

__device__ __forceinline__ void atomAddF(float* p, float v) {
  unsafeAtomicAdd(p, v);       // native ds_add_f32 / global_atomic_add_f32
}

// ---- Pass 1: per-class counts + feature sums ------------------------------
__global__ __launch_bounds__(256) void k_accum(
    const float* __restrict__ pred, const int* __restrict__ tgt,
    float* __restrict__ ws, int nPairs)
{
  __shared__ float s_sums[C_CH * K_CLS];   // [ch][cls]: fixed ch => 19 consecutive words => distinct banks
  __shared__ float s_cnt[K_CLS];
  for (int i = threadIdx.x; i < C_CH * K_CLS; i += 256) s_sums[i] = 0.f;
  if (threadIdx.x < K_CLS) s_cnt[threadIdx.x] = 0.f;
  __syncthreads();

  const int stride = gridDim.x * 256;
  for (int pr = blockIdx.x * 256 + threadIdx.x; pr < nPairs; pr += stride) {
    const int p0 = pr << 1;
    const int n_idx = p0 >> HW_SHIFT;
    const int hw = p0 & (HW_SIZE - 1);
    const int2 ss = *reinterpret_cast<const int2*>(tgt + p0);
    const int s0 = ss.x, s1 = ss.y;
    const bool v0 = (unsigned)s0 < K_CLS;
    const bool v1 = (unsigned)s1 < K_CLS;
    const float* bp = pred + (((size_t)n_idx * C_CH) << HW_SHIFT) + hw;
    if (v0) atomAddF(&s_cnt[s0], 1.f);
    if (v1) atomAddF(&s_cnt[s1], 1.f);
#pragma unroll
    for (int ch = 0; ch < C_CH; ++ch) {
      const float2 v = *reinterpret_cast<const float2*>(bp + ((size_t)ch << HW_SHIFT));
      if (v0) atomAddF(&s_sums[ch * K_CLS + s0], v.x);
      if (v1) atomAddF(&s_sums[ch * K_CLS + s1], v.y);
    }
  }
  __syncthreads();
  for (int i = threadIdx.x; i < C_CH * K_CLS; i += 256) atomAddF(&ws[OFF_SUMS + i], s_sums[i]);
  if (threadIdx.x < K_CLS) atomAddF(&ws[OFF_CNT + threadIdx.x], s_cnt[threadIdx.x]);
}

// ---- Pass 2: per-pixel residuals -> per-class sq / pos --------------------
__global__ __launch_bounds__(256) void k_var(
    const float* __restrict__ pred, const int* __restrict__ tgt,
    float* __restrict__ ws, int nPairs)
{
  __shared__ float s_ctr[C_CH * K_CLS];
  __shared__ float s_sq[K_CLS];
  __shared__ float s_pos[K_CLS];
  for (int i = threadIdx.x; i < C_CH * K_CLS; i += 256) {
    const int s = i % K_CLS;                 // i = ch*19+s -> i%19 == s
    s_ctr[i] = ws[OFF_SUMS + i] / fmaxf(ws[OFF_CNT + s], 1.f);
  }
  if (threadIdx.x < K_CLS) { s_sq[threadIdx.x] = 0.f; s_pos[threadIdx.x] = 0.f; }
  __syncthreads();

  const int stride = gridDim.x * 256;
  for (int pr = blockIdx.x * 256 + threadIdx.x; pr < nPairs; pr += stride) {
    const int p0 = pr << 1;
    const int n_idx = p0 >> HW_SHIFT;
    const int hw = p0 & (HW_SIZE - 1);
    const int2 ss = *reinterpret_cast<const int2*>(tgt + p0);
    const int s0 = ss.x, s1 = ss.y;
    const bool v0 = (unsigned)s0 < K_CLS;
    const bool v1 = (unsigned)s1 < K_CLS;
    const int i0 = v0 ? s0 : 0;              // clamp to keep LDS index in range
    const int i1 = v1 ? s1 : 0;
    const float* bp = pred + (((size_t)n_idx * C_CH) << HW_SHIFT) + hw;
    float d0 = 0.f, d1 = 0.f;
#pragma unroll
    for (int ch = 0; ch < C_CH; ++ch) {
      const float2 v = *reinterpret_cast<const float2*>(bp + ((size_t)ch << HW_SHIFT));
      const float c0 = s_ctr[ch * K_CLS + i0];
      const float c1 = s_ctr[ch * K_CLS + i1];
      const float t0 = c0 - v.x, t1 = c1 - v.y;
      d0 = fmaf(t0, t0, d0);
      d1 = fmaf(t1, t1, d1);
    }
    if (v0) {
      const float r = sqrtf(d0 + EPSF) - THEA_F;
      if (r > 0.f) { atomAddF(&s_sq[s0], r * r); atomAddF(&s_pos[s0], 1.f); }
    }
    if (v1) {
      const float r = sqrtf(d1 + EPSF) - THEA_F;
      if (r > 0.f) { atomAddF(&s_sq[s1], r * r); atomAddF(&s_pos[s1], 1.f); }
    }
  }
  __syncthreads();
  if (threadIdx.x < K_CLS) {
    atomAddF(&ws[OFF_SQ + threadIdx.x], s_sq[threadIdx.x]);
    atomAddF(&ws[OFF_POS + threadIdx.x], s_pos[threadIdx.x]);
  }
}

// ---- Finalize: loss_var + loss_dis + 0.001*loss_reg -----------------------
__global__ __launch_bounds__(384) void k_final(
    const float* __restrict__ ws, float* __restrict__ out)
{
  __shared__ float s_ctr[C_CH * K_CLS];
  __shared__ float s_valid[K_CLS];
  __shared__ float s_red[3];
  __shared__ float s_ncls;
  const int t = threadIdx.x;
  if (t < 3) s_red[t] = 0.f;
  if (t < K_CLS) s_valid[t] = (ws[OFF_CNT + t] > MIN_PIX) ? 1.f : 0.f;
  for (int i = t; i < C_CH * K_CLS; i += 384) {
    const int s = i % K_CLS;
    s_ctr[i] = ws[OFF_SUMS + i] / fmaxf(ws[OFF_CNT + s], 1.f);
  }
  __syncthreads();
  if (t == 0) {
    float n = 0.f;
    for (int k = 0; k < K_CLS; ++k) n += s_valid[k];
    s_ncls = fmaxf(n, 1.f);
  }
  if (t < K_CLS && s_valid[t] > 0.f) {
    // variance term numerator
    atomAddF(&s_red[0], ws[OFF_SQ + t] / fmaxf(ws[OFF_POS + t], 1.f));
    // regularization term
    float nn = 0.f;
#pragma unroll
    for (int ch = 0; ch < C_CH; ++ch) {
      const float cv = s_ctr[ch * K_CLS + t];
      nn = fmaf(cv, cv, nn);
    }
    atomAddF(&s_red[2], sqrtf(nn + EPSF));
  }
  if (t < K_CLS * K_CLS) {
    const int a = t / K_CLS, b = t - (t / K_CLS) * K_CLS;
    if (a != b && s_valid[a] > 0.f && s_valid[b] > 0.f) {
      float dd = 0.f;
#pragma unroll
      for (int ch = 0; ch < C_CH; ++ch) {
        const float df = s_ctr[ch * K_CLS + a] - s_ctr[ch * K_CLS + b];
        dd = fmaf(df, df, dd);
      }
      const float dist = sqrtf(dd + EPSF);
      const float d = fmaxf(TWO_DELTA - dist, 0.f);
      if (d > 0.f) atomAddF(&s_red[1], d * d);
    }
  }
  __syncthreads();
  if (t == 0) {
    const float n = s_ncls;
    out[0] = s_red[0] / n
           + s_red[1] / fmaxf(n * (n - 1.f), 1.f)
           + 0.001f * s_red[2] / n;
  }
}

extern "C" void kernel_launch(void* const* d_in, const int* in_sizes, int n_in,
                              void* d_out, int out_size, void* d_ws, size_t ws_size,
                              hipStream_t stream) {
  const float* pred = (const float*)d_in[0];
  const int*   tgt  = (const int*)d_in[1];
  float* ws  = (float*)d_ws;
  float* out = (float*)d_out;
  const int P = in_sizes[1];        // n*h*w = 2097152
  const int nPairs = P >> 1;

  hipMemsetAsync(d_ws, 0, WS_FLOATS * sizeof(float), stream);
  k_accum<<<1024, 256, 0, stream>>>(pred, tgt, ws, nPairs);
  k_var  <<<1024, 256, 0, stream>>>(pred, tgt, ws, nPairs);
  k_final<<<1, 384, 0, stream>>>(ws, out);
}

// Round 2
// 698.196 us; speedup vs baseline: 1.0059x; 1.0059x over previous
//
#include <hip/hip_runtime.h>

// HNM discriminative loss, MI355X — R2.
// predict (4,32,512,1024) f32, target (4,512,1024) i32 -> scalar f32.
// Block = 2048-pixel contiguous chunk; channel phases outer loop; software-
// pipelined float4 loads (fix R1's VGPR=8 serialized-load codegen).

#define K_CLS 19
#define C_CH 32
#define HW_SHIFT 19            // H*W = 512*1024 = 2^19
#define HW_SIZE (1 << HW_SHIFT)
#define CHUNK 2048             // pixels per block
#define EPSF 1e-12f
#define THEA_F 0.5f
#define TWO_DELTA 3.0f
#define MIN_PIX 20.0f

// ws float layout
#define OFF_SUMS 0             // 608 floats, [ch][cls] = ch*19 + s
#define OFF_CNT  608           // 19
#define OFF_SQ   627           // 19
#define OFF_POS  646           // 19
#define WS_FLOATS 665

__device__ __forceinline__ void atomAddF(float* p, float v) {
  unsafeAtomicAdd(p, v);       // native ds_add_f32 / global_atomic_add_f32
}

// ---- Pass 1: per-class counts + feature sums ------------------------------
__global__ __launch_bounds__(256) void k_accum(
    const float* __restrict__ pred, const int* __restrict__ tgt,
    float* __restrict__ ws)
{
  // [ch][replica][20]: replica per quarter-wave cuts atomic serialization
  __shared__ float s_sums[C_CH][4][20];
  __shared__ float s_cnt[4][20];
  {
    float* z = &s_sums[0][0][0];
    for (int i = threadIdx.x; i < C_CH * 4 * 20; i += 256) z[i] = 0.f;
    float* z2 = &s_cnt[0][0];
    for (int i = threadIdx.x; i < 4 * 20; i += 256) z2[i] = 0.f;
  }

  const int t = threadIdx.x;
  const int rep = (t >> 4) & 3;
  const size_t P0 = (size_t)blockIdx.x * CHUNK;      // chunk never crosses image
  const int n_idx = (int)(P0 >> HW_SHIFT);
  const int hw0 = (int)(P0 & (HW_SIZE - 1));

  // classes for this thread's 8 pixels (held in regs across all phases)
  const int4 t0 = *reinterpret_cast<const int4*>(tgt + P0 + t * 4);
  const int4 t1 = *reinterpret_cast<const int4*>(tgt + P0 + 1024 + t * 4);
  int  sc[8] = {t0.x, t0.y, t0.z, t0.w, t1.x, t1.y, t1.z, t1.w};
  bool vl[8];
#pragma unroll
  for (int i = 0; i < 8; ++i) { vl[i] = (unsigned)sc[i] < K_CLS; if (!vl[i]) sc[i] = 0; }

  __syncthreads();

#pragma unroll
  for (int i = 0; i < 8; ++i) if (vl[i]) atomAddF(&s_cnt[rep][sc[i]], 1.f);

  const float* base = pred + (((size_t)n_idx * C_CH) << HW_SHIFT) + hw0;
  // software pipeline: prefetch next phase's loads before consuming current
  float4 a = *reinterpret_cast<const float4*>(base + t * 4);
  float4 b = *reinterpret_cast<const float4*>(base + 1024 + t * 4);
  for (int ch = 0; ch < C_CH; ++ch) {
    float4 na, nb;
    if (ch < C_CH - 1) {
      const float* p = base + ((size_t)(ch + 1) << HW_SHIFT);
      na = *reinterpret_cast<const float4*>(p + t * 4);
      nb = *reinterpret_cast<const float4*>(p + 1024 + t * 4);
    }
    const float x[8] = {a.x, a.y, a.z, a.w, b.x, b.y, b.z, b.w};
#pragma unroll
    for (int i = 0; i < 8; ++i) if (vl[i]) atomAddF(&s_sums[ch][rep][sc[i]], x[i]);
    a = na; b = nb;
  }

  __syncthreads();
  for (int i = t; i < C_CH * K_CLS; i += 256) {
    const int ch = i / K_CLS, k = i - ch * K_CLS;
    const float v = s_sums[ch][0][k] + s_sums[ch][1][k] + s_sums[ch][2][k] + s_sums[ch][3][k];
    atomAddF(&ws[OFF_SUMS + i], v);
  }
  if (t < K_CLS)
    atomAddF(&ws[OFF_CNT + t], s_cnt[0][t] + s_cnt[1][t] + s_cnt[2][t] + s_cnt[3][t]);
}

// ---- Pass 2: per-pixel residuals (d^2 in registers) -> sq / pos -----------
__global__ __launch_bounds__(256) void k_var(
    const float* __restrict__ pred, const int* __restrict__ tgt,
    float* __restrict__ ws)
{
  __shared__ float s_ctr[C_CH][K_CLS];
  __shared__ float s_sq[K_CLS];
  __shared__ float s_pos[K_CLS];
  for (int i = threadIdx.x; i < C_CH * K_CLS; i += 256) {
    const int k = i % K_CLS;
    s_ctr[0][0] = s_ctr[0][0];  // no-op to keep layout flat-indexable
    (&s_ctr[0][0])[i] = ws[OFF_SUMS + i] / fmaxf(ws[OFF_CNT + k], 1.f);
  }
  if (threadIdx.x < K_CLS) { s_sq[threadIdx.x] = 0.f; s_pos[threadIdx.x] = 0.f; }

  const int t = threadIdx.x;
  const size_t P0 = (size_t)blockIdx.x * CHUNK;
  const int n_idx = (int)(P0 >> HW_SHIFT);
  const int hw0 = (int)(P0 & (HW_SIZE - 1));

  const int4 t0 = *reinterpret_cast<const int4*>(tgt + P0 + t * 4);
  const int4 t1 = *reinterpret_cast<const int4*>(tgt + P0 + 1024 + t * 4);
  int  sc[8] = {t0.x, t0.y, t0.z, t0.w, t1.x, t1.y, t1.z, t1.w};
  bool vl[8];
#pragma unroll
  for (int i = 0; i < 8; ++i) { vl[i] = (unsigned)sc[i] < K_CLS; if (!vl[i]) sc[i] = 0; }

  __syncthreads();

  float d2[8] = {0.f, 0.f, 0.f, 0.f, 0.f, 0.f, 0.f, 0.f};
  const float* base = pred + (((size_t)n_idx * C_CH) << HW_SHIFT) + hw0;
  float4 a = *reinterpret_cast<const float4*>(base + t * 4);
  float4 b = *reinterpret_cast<const float4*>(base + 1024 + t * 4);
  for (int ch = 0; ch < C_CH; ++ch) {
    float4 na, nb;
    if (ch < C_CH - 1) {
      const float* p = base + ((size_t)(ch + 1) << HW_SHIFT);
      na = *reinterpret_cast<const float4*>(p + t * 4);
      nb = *reinterpret_cast<const float4*>(p + 1024 + t * 4);
    }
    const float x[8] = {a.x, a.y, a.z, a.w, b.x, b.y, b.z, b.w};
#pragma unroll
    for (int i = 0; i < 8; ++i) {
      const float c = s_ctr[ch][sc[i]];   // 19 consecutive words: conflict-free
      const float d = c - x[i];
      d2[i] = fmaf(d, d, d2[i]);
    }
    a = na; b = nb;
  }

#pragma unroll
  for (int i = 0; i < 8; ++i) {
    if (vl[i]) {
      const float r = sqrtf(d2[i] + EPSF) - THEA_F;
      if (r > 0.f) { atomAddF(&s_sq[sc[i]], r * r); atomAddF(&s_pos[sc[i]], 1.f); }
    }
  }

  __syncthreads();
  if (t < K_CLS) {
    atomAddF(&ws[OFF_SQ + t], s_sq[t]);
    atomAddF(&ws[OFF_POS + t], s_pos[t]);
  }
}

// ---- Finalize: loss_var + loss_dis + 0.001*loss_reg -----------------------
__global__ __launch_bounds__(384) void k_final(
    const float* __restrict__ ws, float* __restrict__ out)
{
  __shared__ float s_ctr[C_CH * K_CLS];
  __shared__ float s_valid[K_CLS];
  __shared__ float s_red[3];
  __shared__ float s_ncls;
  const int t = threadIdx.x;
  if (t < 3) s_red[t] = 0.f;
  if (t < K_CLS) s_valid[t] = (ws[OFF_CNT + t] > MIN_PIX) ? 1.f : 0.f;
  for (int i = t; i < C_CH * K_CLS; i += 384) {
    const int k = i % K_CLS;
    s_ctr[i] = ws[OFF_SUMS + i] / fmaxf(ws[OFF_CNT + k], 1.f);
  }
  __syncthreads();
  if (t == 0) {
    float n = 0.f;
    for (int k = 0; k < K_CLS; ++k) n += s_valid[k];
    s_ncls = fmaxf(n, 1.f);
  }
  if (t < K_CLS && s_valid[t] > 0.f) {
    atomAddF(&s_red[0], ws[OFF_SQ + t] / fmaxf(ws[OFF_POS + t], 1.f));
    float nn = 0.f;
#pragma unroll
    for (int ch = 0; ch < C_CH; ++ch) {
      const float cv = s_ctr[ch * K_CLS + t];
      nn = fmaf(cv, cv, nn);
    }
    atomAddF(&s_red[2], sqrtf(nn + EPSF));
  }
  if (t < K_CLS * K_CLS) {
    const int a = t / K_CLS, b = t - (t / K_CLS) * K_CLS;
    if (a != b && s_valid[a] > 0.f && s_valid[b] > 0.f) {
      float dd = 0.f;
#pragma unroll
      for (int ch = 0; ch < C_CH; ++ch) {
        const float df = s_ctr[ch * K_CLS + a] - s_ctr[ch * K_CLS + b];
        dd = fmaf(df, df, dd);
      }
      const float dist = sqrtf(dd + EPSF);
      const float d = fmaxf(TWO_DELTA - dist, 0.f);
      if (d > 0.f) atomAddF(&s_red[1], d * d);
    }
  }
  __syncthreads();
  if (t == 0) {
    const float n = s_ncls;
    out[0] = s_red[0] / n
           + s_red[1] / fmaxf(n * (n - 1.f), 1.f)
           + 0.001f * s_red[2] / n;
  }
}

extern "C" void kernel_launch(void* const* d_in, const int* in_sizes, int n_in,
                              void* d_out, int out_size, void* d_ws, size_t ws_size,
                              hipStream_t stream) {
  const float* pred = (const float*)d_in[0];
  const int*   tgt  = (const int*)d_in[1];
  float* ws  = (float*)d_ws;
  float* out = (float*)d_out;
  const int P = in_sizes[1];            // n*h*w = 2097152
  const int nBlocks = P / CHUNK;        // 1024

  hipMemsetAsync(d_ws, 0, WS_FLOATS * sizeof(float), stream);
  k_accum<<<nBlocks, 256, 0, stream>>>(pred, tgt, ws);
  k_var  <<<nBlocks, 256, 0, stream>>>(pred, tgt, ws);
  k_final<<<1, 384, 0, stream>>>(ws, out);
}

// Round 3
// 677.362 us; speedup vs baseline: 1.0368x; 1.0308x over previous
//
#include <hip/hip_runtime.h>

// HNM discriminative loss, MI355X — R3.
// predict (4,32,512,1024) f32, target (4,512,1024) i32 -> scalar f32.
// R3: force 8 outstanding float4 loads per wave per batch (explicit register
// array, unroll-1 batch loop) to break the load->vmcnt(0)->consume
// serialization the compiler emitted in R1/R2 (VGPR 8/20).

#define K_CLS 19
#define C_CH 32
#define HW_SHIFT 19            // H*W = 512*1024 = 2^19
#define HW_SIZE (1 << HW_SHIFT)
#define CHUNK 2048             // pixels per block
#define NB 8                   // channel batches
#define BCH 4                  // channels per batch (NB*BCH == C_CH)
#define EPSF 1e-12f
#define THEA_F 0.5f
#define TWO_DELTA 3.0f
#define MIN_PIX 20.0f

// ws float layout
#define OFF_SUMS 0             // 608 floats, [ch][cls] = ch*19 + s
#define OFF_CNT  608           // 19
#define OFF_SQ   627           // 19
#define OFF_POS  646           // 19
#define WS_FLOATS 665

__device__ __forceinline__ void atomAddF(float* p, float v) {
  unsafeAtomicAdd(p, v);       // native ds_add_f32 / global_atomic_add_f32
}

// ---- Pass 1: per-class counts + feature sums ------------------------------
__global__ __launch_bounds__(256) void k_accum(
    const float* __restrict__ pred, const int* __restrict__ tgt,
    float* __restrict__ ws)
{
  __shared__ float s_sums[C_CH][4][20];   // replica per quarter-wave
  __shared__ float s_cnt[4][20];
  {
    float* z = &s_sums[0][0][0];
    for (int i = threadIdx.x; i < C_CH * 4 * 20; i += 256) z[i] = 0.f;
    if (threadIdx.x < 80) (&s_cnt[0][0])[threadIdx.x] = 0.f;
  }

  const int t = threadIdx.x;
  const int rep = (t >> 4) & 3;
  const size_t P0 = (size_t)blockIdx.x * CHUNK;   // 2048 | 2^19: never crosses image
  const int n_idx = (int)(P0 >> HW_SHIFT);
  const int hw0 = (int)(P0 & (HW_SIZE - 1));

  const int4 t0 = *reinterpret_cast<const int4*>(tgt + P0 + t * 4);
  const int4 t1 = *reinterpret_cast<const int4*>(tgt + P0 + 1024 + t * 4);
  int  sc[8] = {t0.x, t0.y, t0.z, t0.w, t1.x, t1.y, t1.z, t1.w};
  bool vl[8];
#pragma unroll
  for (int i = 0; i < 8; ++i) { vl[i] = (unsigned)sc[i] < K_CLS; if (!vl[i]) sc[i] = 0; }

  __syncthreads();

#pragma unroll
  for (int i = 0; i < 8; ++i) if (vl[i]) atomAddF(&s_cnt[rep][sc[i]], 1.f);

  const float* base = pred + (((size_t)n_idx * C_CH) << HW_SHIFT) + hw0;
#pragma unroll 1
  for (int b = 0; b < NB; ++b) {
    float4 r[2 * BCH];                    // 8 independent loads -> 8 KB/wave in flight
#pragma unroll
    for (int j = 0; j < BCH; ++j) {
      const float* p = base + ((size_t)(b * BCH + j) << HW_SHIFT);
      r[2 * j]     = *reinterpret_cast<const float4*>(p + t * 4);
      r[2 * j + 1] = *reinterpret_cast<const float4*>(p + 1024 + t * 4);
    }
#pragma unroll
    for (int j = 0; j < BCH; ++j) {
      const int ch = b * BCH + j;
      const float x[8] = {r[2*j].x, r[2*j].y, r[2*j].z, r[2*j].w,
                          r[2*j+1].x, r[2*j+1].y, r[2*j+1].z, r[2*j+1].w};
#pragma unroll
      for (int i = 0; i < 8; ++i) if (vl[i]) atomAddF(&s_sums[ch][rep][sc[i]], x[i]);
    }
  }

  __syncthreads();
  for (int i = t; i < C_CH * K_CLS; i += 256) {
    const int ch = i / K_CLS, k = i - ch * K_CLS;
    atomAddF(&ws[OFF_SUMS + i],
             s_sums[ch][0][k] + s_sums[ch][1][k] + s_sums[ch][2][k] + s_sums[ch][3][k]);
  }
  if (t < K_CLS)
    atomAddF(&ws[OFF_CNT + t], s_cnt[0][t] + s_cnt[1][t] + s_cnt[2][t] + s_cnt[3][t]);
}

// ---- Pass 2: per-pixel residuals (d^2 in registers) -> sq / pos -----------
__global__ __launch_bounds__(256) void k_var(
    const float* __restrict__ pred, const int* __restrict__ tgt,
    float* __restrict__ ws)
{
  __shared__ float s_ctr[C_CH][K_CLS];
  __shared__ float s_sq[K_CLS];
  __shared__ float s_pos[K_CLS];
  for (int i = threadIdx.x; i < C_CH * K_CLS; i += 256) {
    const int k = i % K_CLS;
    (&s_ctr[0][0])[i] = ws[OFF_SUMS + i] / fmaxf(ws[OFF_CNT + k], 1.f);
  }
  if (threadIdx.x < K_CLS) { s_sq[threadIdx.x] = 0.f; s_pos[threadIdx.x] = 0.f; }

  const int t = threadIdx.x;
  const size_t P0 = (size_t)blockIdx.x * CHUNK;
  const int n_idx = (int)(P0 >> HW_SHIFT);
  const int hw0 = (int)(P0 & (HW_SIZE - 1));

  const int4 t0 = *reinterpret_cast<const int4*>(tgt + P0 + t * 4);
  const int4 t1 = *reinterpret_cast<const int4*>(tgt + P0 + 1024 + t * 4);
  int  sc[8] = {t0.x, t0.y, t0.z, t0.w, t1.x, t1.y, t1.z, t1.w};
  bool vl[8];
#pragma unroll
  for (int i = 0; i < 8; ++i) { vl[i] = (unsigned)sc[i] < K_CLS; if (!vl[i]) sc[i] = 0; }

  __syncthreads();

  float d2[8] = {0.f, 0.f, 0.f, 0.f, 0.f, 0.f, 0.f, 0.f};
  const float* base = pred + (((size_t)n_idx * C_CH) << HW_SHIFT) + hw0;
#pragma unroll 1
  for (int b = 0; b < NB; ++b) {
    float4 r[2 * BCH];
#pragma unroll
    for (int j = 0; j < BCH; ++j) {
      const float* p = base + ((size_t)(b * BCH + j) << HW_SHIFT);
      r[2 * j]     = *reinterpret_cast<const float4*>(p + t * 4);
      r[2 * j + 1] = *reinterpret_cast<const float4*>(p + 1024 + t * 4);
    }
#pragma unroll
    for (int j = 0; j < BCH; ++j) {
      const int ch = b * BCH + j;
      const float x[8] = {r[2*j].x, r[2*j].y, r[2*j].z, r[2*j].w,
                          r[2*j+1].x, r[2*j+1].y, r[2*j+1].z, r[2*j+1].w};
#pragma unroll
      for (int i = 0; i < 8; ++i) {
        const float c = s_ctr[ch][sc[i]];   // 19 consecutive words: conflict-free
        const float d = c - x[i];
        d2[i] = fmaf(d, d, d2[i]);
      }
    }
  }

#pragma unroll
  for (int i = 0; i < 8; ++i) {
    if (vl[i]) {
      const float r = sqrtf(d2[i] + EPSF) - THEA_F;
      if (r > 0.f) { atomAddF(&s_sq[sc[i]], r * r); atomAddF(&s_pos[sc[i]], 1.f); }
    }
  }

  __syncthreads();
  if (t < K_CLS) {
    atomAddF(&ws[OFF_SQ + t], s_sq[t]);
    atomAddF(&ws[OFF_POS + t], s_pos[t]);
  }
}

// ---- Finalize: loss_var + loss_dis + 0.001*loss_reg -----------------------
__global__ __launch_bounds__(384) void k_final(
    const float* __restrict__ ws, float* __restrict__ out)
{
  __shared__ float s_ctr[C_CH * K_CLS];
  __shared__ float s_valid[K_CLS];
  __shared__ float s_red[3];
  __shared__ float s_ncls;
  const int t = threadIdx.x;
  if (t < 3) s_red[t] = 0.f;
  if (t < K_CLS) s_valid[t] = (ws[OFF_CNT + t] > MIN_PIX) ? 1.f : 0.f;
  for (int i = t; i < C_CH * K_CLS; i += 384) {
    const int k = i % K_CLS;
    s_ctr[i] = ws[OFF_SUMS + i] / fmaxf(ws[OFF_CNT + k], 1.f);
  }
  __syncthreads();
  if (t == 0) {
    float n = 0.f;
    for (int k = 0; k < K_CLS; ++k) n += s_valid[k];
    s_ncls = fmaxf(n, 1.f);
  }
  if (t < K_CLS && s_valid[t] > 0.f) {
    atomAddF(&s_red[0], ws[OFF_SQ + t] / fmaxf(ws[OFF_POS + t], 1.f));
    float nn = 0.f;
#pragma unroll
    for (int ch = 0; ch < C_CH; ++ch) {
      const float cv = s_ctr[ch * K_CLS + t];
      nn = fmaf(cv, cv, nn);
    }
    atomAddF(&s_red[2], sqrtf(nn + EPSF));
  }
  if (t < K_CLS * K_CLS) {
    const int a = t / K_CLS, b = t - (t / K_CLS) * K_CLS;
    if (a != b && s_valid[a] > 0.f && s_valid[b] > 0.f) {
      float dd = 0.f;
#pragma unroll
      for (int ch = 0; ch < C_CH; ++ch) {
        const float df = s_ctr[ch * K_CLS + a] - s_ctr[ch * K_CLS + b];
        dd = fmaf(df, df, dd);
      }
      const float dist = sqrtf(dd + EPSF);
      const float d = fmaxf(TWO_DELTA - dist, 0.f);
      if (d > 0.f) atomAddF(&s_red[1], d * d);
    }
  }
  __syncthreads();
  if (t == 0) {
    const float n = s_ncls;
    out[0] = s_red[0] / n
           + s_red[1] / fmaxf(n * (n - 1.f), 1.f)
           + 0.001f * s_red[2] / n;
  }
}

extern "C" void kernel_launch(void* const* d_in, const int* in_sizes, int n_in,
                              void* d_out, int out_size, void* d_ws, size_t ws_size,
                              hipStream_t stream) {
  const float* pred = (const float*)d_in[0];
  const int*   tgt  = (const int*)d_in[1];
  float* ws  = (float*)d_ws;
  float* out = (float*)d_out;
  const int P = in_sizes[1];            // n*h*w = 2097152
  const int nBlocks = P / CHUNK;        // 1024

  hipMemsetAsync(d_ws, 0, WS_FLOATS * sizeof(float), stream);
  k_accum<<<nBlocks, 256, 0, stream>>>(pred, tgt, ws);
  k_var  <<<nBlocks, 256, 0, stream>>>(pred, tgt, ws);
  k_final<<<1, 384, 0, stream>>>(ws, out);
}